// Round 8
// baseline (128.081 us; speedup 1.0000x reference)
//
#include <hip/hip_runtime.h>

#define TPB 64

constexpr int NSEQ = 32768;
constexpr int C0   = 1024;               // output samples per block chunk (32 chunks/batch)
constexpr float SCG = 14.4269504089f;    // 10 * log2(e)

// Halos h_l = 2*h_{l+1}+3, h5=4 -> {221,109,53,25,11,4}
// C0=1024 padded level widths P (chain P_{l-1} >= 2*P_l+6, mult 4): {760,376,184,88,40}
// Parity arrays per channel [E|O], LE = P+4: {764,380,188,92,44}; L5 out contiguous stride 40
// Synthesis strides {72,136,264,520}; every LDS slot read is provably written.
// bufA: L0(1528) L2(1504) L4(1408) recon4(1152) recon2(1056) -> 1528
// bufB: L1(1520) L3(1472) L5(1280) recon3(1088) recon1(1040) -> 1520
// LDS = (1528+1520+62)*4 = 12440 B -> 12 single-wave blocks/CU, all barrier-free
// (workgroup == wave: compiler removes s_barrier; __syncthreads -> waitcnt only).

__device__ __forceinline__ float4 ldf4(const float* p) { return *reinterpret_cast<const float4*>(p); }
__device__ __forceinline__ void   stf4(float* p, const float4 v) { *reinterpret_cast<float4*>(p) = v; }

__device__ __forceinline__ float rfl(float x) {
    return __builtin_bit_cast(float, __builtin_amdgcn_readfirstlane(__builtin_bit_cast(int, x)));
}

// y * (sigmoid(10(y-b)) + sigmoid(-10(y+b))), tb = SCG*b precomputed
__device__ __forceinline__ float gated(float y, float tb) {
    float e1 = __builtin_amdgcn_exp2f(fmaf(y, -SCG, tb));
    float e2 = __builtin_amdgcn_exp2f(fmaf(y,  SCG, tb));
    return y * (__builtin_amdgcn_rcpf(1.f + e1) + __builtin_amdgcn_rcpf(1.f + e2));
}

// Analysis level, r=4 (dense LDS): task = 4 outputs for sibling channels 2c,2c+1.
// in[2i+t] = E[i+t/2] (t even) / O[i+(t-1)/2] (t odd); window base s-221 makes this
// hold at L1 too.  Reads: 2x b128 per parity array, 16B lane stride, dense+aligned.
// Writes: parity float2 (8B stride dense) or contiguous float4 (LAST).
template<int LEin, int LEout, int P, int PAIRS, int Nlev, bool EDGE, bool LAST>
__device__ __forceinline__ void analysis4(
    const float* __restrict__ in, float* __restrict__ out,
    const float* __restrict__ lp, const float* __restrict__ hp,
    const float* __restrict__ bias, int outBase)
{
    constexpr int TPC = P / 4;
    constexpr int TOT = PAIRS * TPC;
    for (int task = threadIdx.x; task < TOT; task += TPB) {
        const int c  = task / TPC;
        const int i0 = (task - c * TPC) * 4;

        const float* pe = in + c * (2 * LEin) + i0;
        const float* po = pe + LEin;
        float a[8], b[8];
        reinterpret_cast<float4*>(a)[0] = ldf4(pe);
        reinterpret_cast<float4*>(a)[1] = ldf4(pe + 4);
        reinterpret_cast<float4*>(b)[0] = ldf4(po);
        reinterpret_cast<float4*>(b)[1] = ldf4(po + 4);

        const int sw     = c & 1;
        const int ch_lp  = 2 * c + sw;
        const int ch_hp  = 2 * c + 1 - sw;
        const float tb_l = bias[ch_lp];
        const float tb_h = bias[ch_hp];

        float vl[4], vh[4];
#pragma unroll
        for (int r = 0; r < 4; ++r) {
            float yl = 0.f, yh = 0.f;
#pragma unroll
            for (int u = 0; u < 4; ++u) {
                yl = fmaf(a[r + u], lp[2 * u], yl);
                yl = fmaf(b[r + u], lp[2 * u + 1], yl);
                yh = fmaf(a[r + u], hp[2 * u], yh);
                yh = fmaf(b[r + u], hp[2 * u + 1], yh);
            }
            float wl = gated(yl, tb_l);
            float wh = gated(yh, tb_h);
            if (EDGE) {
                const bool ok = ((unsigned)(outBase + i0 + r) < (unsigned)Nlev);
                wl = ok ? wl : 0.f;
                wh = ok ? wh : 0.f;
            }
            vl[r] = wl; vh[r] = wh;
        }

        if (LAST) {
            stf4(out + ch_lp * LEout + i0, make_float4(vl[0], vl[1], vl[2], vl[3]));
            stf4(out + ch_hp * LEout + i0, make_float4(vh[0], vh[1], vh[2], vh[3]));
        } else {
            const int j0 = i0 >> 1;
            float* ol = out + ch_lp * (2 * LEout);
            float* oh = out + ch_hp * (2 * LEout);
            *reinterpret_cast<float2*>(ol + j0)         = make_float2(vl[0], vl[2]);
            *reinterpret_cast<float2*>(ol + LEout + j0) = make_float2(vl[1], vl[3]);
            *reinterpret_cast<float2*>(oh + j0)         = make_float2(vh[0], vh[2]);
            *reinterpret_cast<float2*>(oh + LEout + j0) = make_float2(vh[1], vh[3]);
        }
    }
}

// Synthesis r=8 (reads 16B-stride dense; writes 32B stride, 4-way, ~free):
// out[g,nl] = sum_q y_lp[j0+q]*lp[kb-2q] + y_hp[j0+q]*hp[kb-2q]
// lp-channel of group g is 2g+(g&1); j0=(nl+1)>>1 local, kb=7-(nl&1).
template<int Sin, int Sout, int G, int Nlev, bool EDGE>
__device__ __forceinline__ void synth8(
    const float* __restrict__ in, float* __restrict__ out,
    const float* __restrict__ lp, const float* __restrict__ hp, int outBase)
{
    constexpr int TPG = Sout / 8;
    constexpr int TOT = G * TPG;
    for (int task = threadIdx.x; task < TOT; task += TPB) {
        const int g   = task / TPG;
        const int nl0 = (task - g * TPG) * 8;
        const int sw  = g & 1;

        float ya[8], yb[8];
        {
            const float* p0 = in + (2 * g + sw)     * Sin + nl0 / 2;   // lp channel
            const float* p1 = in + (2 * g + 1 - sw) * Sin + nl0 / 2;   // hp channel
            reinterpret_cast<float4*>(ya)[0] = ldf4(p0);
            reinterpret_cast<float4*>(ya)[1] = ldf4(p0 + 4);
            reinterpret_cast<float4*>(yb)[0] = ldf4(p1);
            reinterpret_cast<float4*>(yb)[1] = ldf4(p1 + 4);
        }

        float o[8];
#pragma unroll
        for (int r = 0; r < 8; ++r) {
            const int jr = (r + 1) >> 1;
            const int kb = 7 - (r & 1);
            float acc = 0.f;
#pragma unroll
            for (int q = 0; q < 4; ++q) {
                acc = fmaf(ya[jr + q], lp[kb - 2 * q], acc);
                acc = fmaf(yb[jr + q], hp[kb - 2 * q], acc);
            }
            if (EDGE) {
                const bool ok = ((unsigned)(outBase + nl0 + r) < (unsigned)Nlev);
                acc = ok ? acc : 0.f;
            }
            o[r] = acc;
        }
        float* op = out + g * Sout + nl0;
        stf4(op,     make_float4(o[0], o[1], o[2], o[3]));
        stf4(op + 4, make_float4(o[4], o[5], o[6], o[7]));
    }
}

template<bool EDGE>
__device__ __forceinline__ void run_chunk(
    const float* __restrict__ xb, float* __restrict__ ob, int s,
    float* __restrict__ bufA, float* __restrict__ bufB,
    const float* __restrict__ lp, const float* __restrict__ hp,
    const float* __restrict__ bss)
{
    const int tid = threadIdx.x;

    // Stage x window, base s-221: E[j]=x[base+2j] (bufA[0..763]), O[j]=x[base+2j+1]
    {
        const int base = s - 221;
        for (int j = tid; j < 764; j += TPB) {
            const int g0 = base + 2 * j;
            if (EDGE) {
                bufA[j]       = ((unsigned)g0       < (unsigned)NSEQ) ? xb[g0]     : 0.f;
                bufA[764 + j] = ((unsigned)(g0 + 1) < (unsigned)NSEQ) ? xb[g0 + 1] : 0.f;
            } else {
                bufA[j]       = xb[g0];
                bufA[764 + j] = xb[g0 + 1];
            }
        }
    }
    __syncthreads();

    // ---- analysis (r=4, parity ping-pong) ----
    analysis4<764, 380, 760,  1, 16384, EDGE, false>(bufA, bufB, lp, hp, bss + 0,  (s >> 1) - 109);
    __syncthreads();
    analysis4<380, 188, 376,  2,  8192, EDGE, false>(bufB, bufA, lp, hp, bss + 2,  (s >> 2) - 53);
    __syncthreads();
    analysis4<188,  92, 184,  4,  4096, EDGE, false>(bufA, bufB, lp, hp, bss + 6,  (s >> 3) - 25);
    __syncthreads();
    analysis4< 92,  44,  88,  8,  2048, EDGE, false>(bufB, bufA, lp, hp, bss + 14, (s >> 4) - 11);
    __syncthreads();
    analysis4< 44,  40,  40, 16,  1024, EDGE, true >(bufA, bufB, lp, hp, bss + 30, (s >> 5) - 4);
    __syncthreads();

    // ---- synthesis ----
    synth8< 40,  72, 16,  2048, EDGE>(bufB, bufA, lp, hp, (s >> 4) - 4);
    __syncthreads();
    synth8< 72, 136,  8,  4096, EDGE>(bufA, bufB, lp, hp, (s >> 3) - 4);
    __syncthreads();
    synth8<136, 264,  4,  8192, EDGE>(bufB, bufA, lp, hp, (s >> 2) - 4);
    __syncthreads();
    synth8<264, 520,  2, 16384, EDGE>(bufA, bufB, lp, hp, (s >> 1) - 4);
    __syncthreads();

    // ---- final level (G=1) straight to global; recon1 in bufB, stride 520, base s/2-4 ----
    for (int task = tid; task < 128; task += TPB) {
        const int i0 = task * 8;
        float ya[12], yb[12];
        {
            const float* p0 = bufB + i0 / 2;          // channel 0 = lp
            const float* p1 = p0 + 520;               // channel 1 = hp
            reinterpret_cast<float4*>(ya)[0] = ldf4(p0);
            reinterpret_cast<float4*>(ya)[1] = ldf4(p0 + 4);
            reinterpret_cast<float4*>(ya)[2] = ldf4(p0 + 8);
            reinterpret_cast<float4*>(yb)[0] = ldf4(p1);
            reinterpret_cast<float4*>(yb)[1] = ldf4(p1 + 4);
            reinterpret_cast<float4*>(yb)[2] = ldf4(p1 + 8);
        }
        float o[8];
#pragma unroll
        for (int r = 0; r < 8; ++r) {
            const int jr = ((r + 1) >> 1) + 2;
            const int kb = 7 - (r & 1);
            float acc = 0.f;
#pragma unroll
            for (int q = 0; q < 4; ++q) {
                acc = fmaf(ya[jr + q], lp[kb - 2 * q], acc);
                acc = fmaf(yb[jr + q], hp[kb - 2 * q], acc);
            }
            o[r] = acc;
        }
        stf4(ob + i0,     make_float4(o[0], o[1], o[2], o[3]));
        stf4(ob + i0 + 4, make_float4(o[4], o[5], o[6], o[7]));
    }
}

__global__ __launch_bounds__(TPB) void wpt_fused(
    const float* __restrict__ x,
    const float* __restrict__ K1, const float* __restrict__ K2,
    const float* __restrict__ K3, const float* __restrict__ K4,
    const float* __restrict__ K5,
    const float* __restrict__ B1, const float* __restrict__ B2,
    const float* __restrict__ B3, const float* __restrict__ B4,
    const float* __restrict__ B5,
    float* __restrict__ out)
{
    __shared__ __align__(16) float bufA[1528];
    __shared__ __align__(16) float bufB[1520];
    __shared__ float bss[62];

    const int tid   = threadIdx.x;
    const int batch = blockIdx.x >> 5;
    const int cid   = blockIdx.x & 31;
    const int s     = cid * C0;

    // Filters in SGPRs: K1 = [lp | hp]; every level's rows are one of these two.
    float lp[8], hp[8];
#pragma unroll
    for (int t = 0; t < 8; ++t) {
        lp[t] = rfl(K1[t]);
        hp[t] = rfl(K1[8 + t]);
    }

    // Biases (pre-scaled by 10*log2(e))
    {
        const float* bin[5] = {B1, B2, B3, B4, B5};
        const int boff[5] = {0, 2, 6, 14, 30};
#pragma unroll
        for (int l = 0; l < 5; ++l)
            for (int i = tid; i < (2 << l); i += TPB) bss[boff[l] + i] = SCG * bin[l][i];
    }

    const float* xb = x + batch * NSEQ;
    float* ob = out + batch * NSEQ + s;

    if (cid == 0 || cid == 31)
        run_chunk<true >(xb, ob, s, bufA, bufB, lp, hp, bss);
    else
        run_chunk<false>(xb, ob, s, bufA, bufB, lp, hp, bss);
}

extern "C" void kernel_launch(void* const* d_in, const int* in_sizes, int n_in,
                              void* d_out, int out_size, void* d_ws, size_t ws_size,
                              hipStream_t stream) {
    const int nbatch = in_sizes[0] / NSEQ;
    wpt_fused<<<dim3(nbatch * (NSEQ / C0)), dim3(TPB), 0, stream>>>(
        (const float*)d_in[0],
        (const float*)d_in[1], (const float*)d_in[2],
        (const float*)d_in[3], (const float*)d_in[4],
        (const float*)d_in[5],
        (const float*)d_in[6], (const float*)d_in[7],
        (const float*)d_in[8], (const float*)d_in[9],
        (const float*)d_in[10],
        (float*)d_out);
}

// Round 9
// 123.992 us; speedup vs baseline: 1.0330x; 1.0330x over previous
//
#include <hip/hip_runtime.h>

#define TPB 128

constexpr int NSEQ = 32768;
constexpr int C0   = 1024;               // output samples per block chunk (32 chunks/batch)
constexpr float SCG = 14.4269504089f;    // 10 * log2(e)

// Halos h_l = 2*h_{l+1}+3, h5=4 -> {221,109,53,25,11,4}
// C0=1024 padded level widths P: {760,376,184,88,40}; parity arrays [E|O], LE=P+4:
// {764,380,188,92,44}. L5 fused into synthesis (no L5 buffer).
// Ping-pong: L0:A L1:B L2:A L3:B L4:A recon4:B recon3:A recon2:B recon1:A.
// bufA max(1528,1504,1408,1088,1040)=1528; bufB max(1520,1472,1152,1056)=1520.
// LDS = (1528+1520+62)*4 = 12440 B -> 12 blocks * 2 waves = 24 waves/CU.

__device__ __forceinline__ float4 ldf4(const float* p) { return *reinterpret_cast<const float4*>(p); }
__device__ __forceinline__ void   stf4(float* p, const float4 v) { *reinterpret_cast<float4*>(p) = v; }

__device__ __forceinline__ float rfl(float x) {
    return __builtin_bit_cast(float, __builtin_amdgcn_readfirstlane(__builtin_bit_cast(int, x)));
}

// y * (sigmoid(10(y-b)) + sigmoid(-10(y+b))), tb = SCG*b precomputed
__device__ __forceinline__ float gated(float y, float tb) {
    float e1 = __builtin_amdgcn_exp2f(fmaf(y, -SCG, tb));
    float e2 = __builtin_amdgcn_exp2f(fmaf(y,  SCG, tb));
    return y * (__builtin_amdgcn_rcpf(1.f + e1) + __builtin_amdgcn_rcpf(1.f + e2));
}

// Analysis level, r=4 (dense LDS): task = 4 outputs for sibling channels 2c,2c+1.
// in[2i+t] = E[i+t/2] (t even) / O[i+(t-1)/2] (t odd); window base s-221 makes this
// hold at L1 too.  ch_lp = 2c+(c&1) (QMF row-parity rule).
template<int LEin, int LEout, int P, int PAIRS, int Nlev, bool EDGE>
__device__ __forceinline__ void analysis4(
    const float* __restrict__ in, float* __restrict__ out,
    const float* __restrict__ lp, const float* __restrict__ hp,
    const float* __restrict__ bias, int outBase)
{
    constexpr int TPC = P / 4;
    constexpr int TOT = PAIRS * TPC;
    for (int task = threadIdx.x; task < TOT; task += TPB) {
        const int c  = task / TPC;
        const int i0 = (task - c * TPC) * 4;

        const float* pe = in + c * (2 * LEin) + i0;
        const float* po = pe + LEin;
        float a[8], b[8];
        reinterpret_cast<float4*>(a)[0] = ldf4(pe);
        reinterpret_cast<float4*>(a)[1] = ldf4(pe + 4);
        reinterpret_cast<float4*>(b)[0] = ldf4(po);
        reinterpret_cast<float4*>(b)[1] = ldf4(po + 4);

        const int sw     = c & 1;
        const int ch_lp  = 2 * c + sw;
        const int ch_hp  = 2 * c + 1 - sw;
        const float tb_l = bias[ch_lp];
        const float tb_h = bias[ch_hp];

        float vl[4], vh[4];
#pragma unroll
        for (int r = 0; r < 4; ++r) {
            float yl = 0.f, yh = 0.f;
#pragma unroll
            for (int u = 0; u < 4; ++u) {
                yl = fmaf(a[r + u], lp[2 * u], yl);
                yl = fmaf(b[r + u], lp[2 * u + 1], yl);
                yh = fmaf(a[r + u], hp[2 * u], yh);
                yh = fmaf(b[r + u], hp[2 * u + 1], yh);
            }
            float wl = gated(yl, tb_l);
            float wh = gated(yh, tb_h);
            if (EDGE) {
                const bool ok = ((unsigned)(outBase + i0 + r) < (unsigned)Nlev);
                wl = ok ? wl : 0.f;
                wh = ok ? wh : 0.f;
            }
            vl[r] = wl; vh[r] = wh;
        }

        const int j0 = i0 >> 1;
        float* ol = out + ch_lp * (2 * LEout);
        float* oh = out + ch_hp * (2 * LEout);
        *reinterpret_cast<float2*>(ol + j0)         = make_float2(vl[0], vl[2]);
        *reinterpret_cast<float2*>(ol + LEout + j0) = make_float2(vl[1], vl[3]);
        *reinterpret_cast<float2*>(oh + j0)         = make_float2(vh[0], vh[2]);
        *reinterpret_cast<float2*>(oh + LEout + j0) = make_float2(vh[1], vh[3]);
    }
}

// Fused L5 analysis + L5 synthesis: task = 8 recon4 outputs [nl0..nl0+7] of group g.
// Computes L5 coeffs for channels 2g,2g+1 at j in [nl0/2 .. nl0/2+7] directly from
// L4 parity (channel g, stride 88: E[0..43] | O[44..87]); no L5 buffer/barrier.
template<bool EDGE>
__device__ __forceinline__ void fused_l5(
    const float* __restrict__ in, float* __restrict__ out,
    const float* __restrict__ lp, const float* __restrict__ hp,
    const float* __restrict__ bias, int s)
{
    for (int task = threadIdx.x; task < 16 * 9; task += TPB) {
        const int g   = task / 9;
        const int nl0 = (task - g * 9) * 8;
        const int j0  = nl0 >> 1;            // multiple of 4 -> 16B aligned reads

        const float* pe = in + g * 88 + j0;  // E[j0 .. j0+11] (j0+11 <= 43)
        const float* po = pe + 44;
        float E[12], O[12];
        reinterpret_cast<float4*>(E)[0] = ldf4(pe);
        reinterpret_cast<float4*>(E)[1] = ldf4(pe + 4);
        reinterpret_cast<float4*>(E)[2] = ldf4(pe + 8);
        reinterpret_cast<float4*>(O)[0] = ldf4(po);
        reinterpret_cast<float4*>(O)[1] = ldf4(po + 4);
        reinterpret_cast<float4*>(O)[2] = ldf4(po + 8);

        const int sw = g & 1;
        const float tbl = bias[2 * g + sw];
        const float tbh = bias[2 * g + 1 - sw];

        float ya[8], yb[8];
#pragma unroll
        for (int j = 0; j < 8; ++j) {
            float yl = 0.f, yh = 0.f;
#pragma unroll
            for (int u = 0; u < 4; ++u) {
                yl = fmaf(E[j + u], lp[2 * u], yl);
                yl = fmaf(O[j + u], lp[2 * u + 1], yl);
                yh = fmaf(E[j + u], hp[2 * u], yh);
                yh = fmaf(O[j + u], hp[2 * u + 1], yh);
            }
            float wl = gated(yl, tbl);
            float wh = gated(yh, tbh);
            if (EDGE) {
                const bool ok = ((unsigned)((s >> 5) - 4 + j0 + j) < 1024u);
                wl = ok ? wl : 0.f;
                wh = ok ? wh : 0.f;
            }
            ya[j] = wl; yb[j] = wh;
        }

        float o[8];
#pragma unroll
        for (int r = 0; r < 8; ++r) {
            const int jr = (r + 1) >> 1;
            const int kb = 7 - (r & 1);
            float acc = 0.f;
#pragma unroll
            for (int q = 0; q < 4; ++q) {
                acc = fmaf(ya[jr + q], lp[kb - 2 * q], acc);
                acc = fmaf(yb[jr + q], hp[kb - 2 * q], acc);
            }
            if (EDGE) {
                const bool ok = ((unsigned)((s >> 4) - 4 + nl0 + r) < 2048u);
                acc = ok ? acc : 0.f;
            }
            o[r] = acc;
        }
        float* op = out + g * 72 + nl0;
        stf4(op,     make_float4(o[0], o[1], o[2], o[3]));
        stf4(op + 4, make_float4(o[4], o[5], o[6], o[7]));
    }
}

// Synthesis r=8: out[g,nl] = sum_q y_lp[j0+q]*lp[kb-2q] + y_hp[j0+q]*hp[kb-2q]
// lp-channel of group g is 2g+(g&1); j0=(nl+1)>>1 local, kb=7-(nl&1).
template<int Sin, int Sout, int G, int Nlev, bool EDGE>
__device__ __forceinline__ void synth8(
    const float* __restrict__ in, float* __restrict__ out,
    const float* __restrict__ lp, const float* __restrict__ hp, int outBase)
{
    constexpr int TPG = Sout / 8;
    constexpr int TOT = G * TPG;
    for (int task = threadIdx.x; task < TOT; task += TPB) {
        const int g   = task / TPG;
        const int nl0 = (task - g * TPG) * 8;
        const int sw  = g & 1;

        float ya[8], yb[8];
        {
            const float* p0 = in + (2 * g + sw)     * Sin + nl0 / 2;   // lp channel
            const float* p1 = in + (2 * g + 1 - sw) * Sin + nl0 / 2;   // hp channel
            reinterpret_cast<float4*>(ya)[0] = ldf4(p0);
            reinterpret_cast<float4*>(ya)[1] = ldf4(p0 + 4);
            reinterpret_cast<float4*>(yb)[0] = ldf4(p1);
            reinterpret_cast<float4*>(yb)[1] = ldf4(p1 + 4);
        }

        float o[8];
#pragma unroll
        for (int r = 0; r < 8; ++r) {
            const int jr = (r + 1) >> 1;
            const int kb = 7 - (r & 1);
            float acc = 0.f;
#pragma unroll
            for (int q = 0; q < 4; ++q) {
                acc = fmaf(ya[jr + q], lp[kb - 2 * q], acc);
                acc = fmaf(yb[jr + q], hp[kb - 2 * q], acc);
            }
            if (EDGE) {
                const bool ok = ((unsigned)(outBase + nl0 + r) < (unsigned)Nlev);
                acc = ok ? acc : 0.f;
            }
            o[r] = acc;
        }
        float* op = out + g * Sout + nl0;
        stf4(op,     make_float4(o[0], o[1], o[2], o[3]));
        stf4(op + 4, make_float4(o[4], o[5], o[6], o[7]));
    }
}

template<bool EDGE>
__device__ __forceinline__ void run_chunk(
    const float* __restrict__ xb, float* __restrict__ ob, int s,
    float* __restrict__ bufA, float* __restrict__ bufB,
    const float* __restrict__ lp, const float* __restrict__ hp,
    const float* __restrict__ bss)
{
    const int tid = threadIdx.x;

    // Stage x window: E[j]=x[s-221+2j] (bufA[0..763]), O[j]=x[s-220+2j] (bufA[764..1527])
    if (EDGE) {
        const int base = s - 221;
        for (int j = tid; j < 764; j += TPB) {
            const int g0 = base + 2 * j;
            bufA[j]       = ((unsigned)g0       < (unsigned)NSEQ) ? xb[g0]     : 0.f;
            bufA[764 + j] = ((unsigned)(g0 + 1) < (unsigned)NSEQ) ? xb[g0 + 1] : 0.f;
        }
    } else {
        // Aligned float4 loads from s-224; v=(x[g0..g0+3]) ->
        // O[2t-2]=v.x, E[2t-1]=v.y, O[2t-1]=v.z, E[2t]=v.w
        const float* xa = xb + s - 224;
        for (int t = tid; t < 383; t += TPB) {
            const float4 v = *reinterpret_cast<const float4*>(xa + 4 * t);
            if (t > 0) {
                bufA[2 * t - 1] = v.y;
                *reinterpret_cast<float2*>(bufA + 764 + 2 * t - 2) = make_float2(v.x, v.z);
            }
            if (t < 382) bufA[2 * t] = v.w;
        }
    }
    __syncthreads();

    // ---- analysis (r=4, parity ping-pong) ----
    analysis4<764, 380, 760,  1, 16384, EDGE>(bufA, bufB, lp, hp, bss + 0,  (s >> 1) - 109);
    __syncthreads();
    analysis4<380, 188, 376,  2,  8192, EDGE>(bufB, bufA, lp, hp, bss + 2,  (s >> 2) - 53);
    __syncthreads();
    analysis4<188,  92, 184,  4,  4096, EDGE>(bufA, bufB, lp, hp, bss + 6,  (s >> 3) - 25);
    __syncthreads();
    analysis4< 92,  44,  88,  8,  2048, EDGE>(bufB, bufA, lp, hp, bss + 14, (s >> 4) - 11);
    __syncthreads();

    // ---- fused L5 analysis + synthesis: L4 (bufA) -> recon4 (bufB, stride 72) ----
    fused_l5<EDGE>(bufA, bufB, lp, hp, bss + 30, s);
    __syncthreads();

    // ---- synthesis ----
    synth8< 72, 136,  8,  4096, EDGE>(bufB, bufA, lp, hp, (s >> 3) - 4);
    __syncthreads();
    synth8<136, 264,  4,  8192, EDGE>(bufA, bufB, lp, hp, (s >> 2) - 4);
    __syncthreads();
    synth8<264, 520,  2, 16384, EDGE>(bufB, bufA, lp, hp, (s >> 1) - 4);
    __syncthreads();

    // ---- final level (G=1) straight to global; recon1 in bufA, stride 520, base s/2-4 ----
    for (int task = tid; task < 128; task += TPB) {
        const int i0 = task * 8;
        float ya[12], yb[12];
        {
            const float* p0 = bufA + i0 / 2;          // channel 0 = lp
            const float* p1 = p0 + 520;               // channel 1 = hp
            reinterpret_cast<float4*>(ya)[0] = ldf4(p0);
            reinterpret_cast<float4*>(ya)[1] = ldf4(p0 + 4);
            reinterpret_cast<float4*>(ya)[2] = ldf4(p0 + 8);
            reinterpret_cast<float4*>(yb)[0] = ldf4(p1);
            reinterpret_cast<float4*>(yb)[1] = ldf4(p1 + 4);
            reinterpret_cast<float4*>(yb)[2] = ldf4(p1 + 8);
        }
        float o[8];
#pragma unroll
        for (int r = 0; r < 8; ++r) {
            const int jr = ((r + 1) >> 1) + 2;
            const int kb = 7 - (r & 1);
            float acc = 0.f;
#pragma unroll
            for (int q = 0; q < 4; ++q) {
                acc = fmaf(ya[jr + q], lp[kb - 2 * q], acc);
                acc = fmaf(yb[jr + q], hp[kb - 2 * q], acc);
            }
            o[r] = acc;
        }
        stf4(ob + i0,     make_float4(o[0], o[1], o[2], o[3]));
        stf4(ob + i0 + 4, make_float4(o[4], o[5], o[6], o[7]));
    }
}

__global__ __launch_bounds__(TPB, 6) void wpt_fused(
    const float* __restrict__ x,
    const float* __restrict__ K1, const float* __restrict__ K2,
    const float* __restrict__ K3, const float* __restrict__ K4,
    const float* __restrict__ K5,
    const float* __restrict__ B1, const float* __restrict__ B2,
    const float* __restrict__ B3, const float* __restrict__ B4,
    const float* __restrict__ B5,
    float* __restrict__ out)
{
    __shared__ __align__(16) float bufA[1528];
    __shared__ __align__(16) float bufB[1520];
    __shared__ float bss[62];

    const int tid   = threadIdx.x;
    const int batch = blockIdx.x >> 5;
    const int cid   = blockIdx.x & 31;
    const int s     = cid * C0;

    // Filters in SGPRs: K1 = [lp | hp]; every level's rows are one of these two.
    float lp[8], hp[8];
#pragma unroll
    for (int t = 0; t < 8; ++t) {
        lp[t] = rfl(K1[t]);
        hp[t] = rfl(K1[8 + t]);
    }

    // Biases (pre-scaled by 10*log2(e))
    {
        const float* bin[5] = {B1, B2, B3, B4, B5};
        const int boff[5] = {0, 2, 6, 14, 30};
#pragma unroll
        for (int l = 0; l < 5; ++l)
            for (int i = tid; i < (2 << l); i += TPB) bss[boff[l] + i] = SCG * bin[l][i];
    }

    const float* xb = x + batch * NSEQ;
    float* ob = out + batch * NSEQ + s;

    if (cid == 0 || cid == 31)
        run_chunk<true >(xb, ob, s, bufA, bufB, lp, hp, bss);
    else
        run_chunk<false>(xb, ob, s, bufA, bufB, lp, hp, bss);
}

extern "C" void kernel_launch(void* const* d_in, const int* in_sizes, int n_in,
                              void* d_out, int out_size, void* d_ws, size_t ws_size,
                              hipStream_t stream) {
    const int nbatch = in_sizes[0] / NSEQ;
    wpt_fused<<<dim3(nbatch * (NSEQ / C0)), dim3(TPB), 0, stream>>>(
        (const float*)d_in[0],
        (const float*)d_in[1], (const float*)d_in[2],
        (const float*)d_in[3], (const float*)d_in[4],
        (const float*)d_in[5],
        (const float*)d_in[6], (const float*)d_in[7],
        (const float*)d_in[8], (const float*)d_in[9],
        (const float*)d_in[10],
        (float*)d_out);
}

// Round 10
// 118.907 us; speedup vs baseline: 1.0771x; 1.0428x over previous
//
#include <hip/hip_runtime.h>

#define TPB 192

constexpr int NSEQ = 32768;
constexpr int C0   = 1024;               // output samples per block chunk (32 chunks/batch)
constexpr float SCG = 14.4269504089f;    // 10 * log2(e)

// Halos h_l = 2*h_{l+1}+3, h5=4 -> {221,109,53,25,11,4}
// C0=1024 padded level widths P: {760,376,184,88,40}; parity arrays [E|O], LE=P+4:
// {764,380,188,92,44}; L5 out contiguous stride 40; synthesis strides {72,136,264,520}.
// bufA: L0(1528) L2(1504) L4(1408) recon4(1152) recon2(1056) -> 1528
// bufB: L1(1520) L3(1472) L5(1280) recon3(1088) recon1(1040) -> 1520
// LDS = (1528+1520+62)*4 = 12440 B -> 10 blocks * 3 waves = 30 waves/CU (wave-capped).
// TPB=192 >= max phase task count (190) -> every phase is ONE straight-line guarded
// block (no grid-stride loop): compiler hoists all ds_reads of a phase together.

__device__ __forceinline__ float4 ldf4(const float* p) { return *reinterpret_cast<const float4*>(p); }
__device__ __forceinline__ void   stf4(float* p, const float4 v) { *reinterpret_cast<float4*>(p) = v; }

__device__ __forceinline__ float rfl(float x) {
    return __builtin_bit_cast(float, __builtin_amdgcn_readfirstlane(__builtin_bit_cast(int, x)));
}

// y * (sigmoid(10(y-b)) + sigmoid(-10(y+b))), tb = SCG*b precomputed
__device__ __forceinline__ float gated(float y, float tb) {
    float e1 = __builtin_amdgcn_exp2f(fmaf(y, -SCG, tb));
    float e2 = __builtin_amdgcn_exp2f(fmaf(y,  SCG, tb));
    return y * (__builtin_amdgcn_rcpf(1.f + e1) + __builtin_amdgcn_rcpf(1.f + e2));
}

// Analysis level, r=4 (dense LDS): task = 4 outputs for sibling channels 2c,2c+1.
// in[2i+t] = E[i+t/2] (t even) / O[i+(t-1)/2] (t odd); window base s-221 makes this
// hold at L1 too.  ch_lp = 2c+(c&1) (QMF row-parity rule).  ONE task per thread.
template<int LEin, int LEout, int P, int PAIRS, int Nlev, bool EDGE, bool LAST>
__device__ __forceinline__ void analysis4(
    const float* __restrict__ in, float* __restrict__ out,
    const float* __restrict__ lp, const float* __restrict__ hp,
    const float* __restrict__ bias, int outBase)
{
    constexpr int TPC = P / 4;
    constexpr int TOT = PAIRS * TPC;
    static_assert(TOT <= TPB, "phase must be single-generation");
    const int task = threadIdx.x;
    if (task < TOT) {
        const int c  = task / TPC;
        const int i0 = (task - c * TPC) * 4;

        const float* pe = in + c * (2 * LEin) + i0;
        const float* po = pe + LEin;
        float a[8], b[8];
        reinterpret_cast<float4*>(a)[0] = ldf4(pe);
        reinterpret_cast<float4*>(a)[1] = ldf4(pe + 4);
        reinterpret_cast<float4*>(b)[0] = ldf4(po);
        reinterpret_cast<float4*>(b)[1] = ldf4(po + 4);

        const int sw     = c & 1;
        const int ch_lp  = 2 * c + sw;
        const int ch_hp  = 2 * c + 1 - sw;
        const float tb_l = bias[ch_lp];
        const float tb_h = bias[ch_hp];

        float vl[4], vh[4];
#pragma unroll
        for (int r = 0; r < 4; ++r) {
            float yl = 0.f, yh = 0.f;
#pragma unroll
            for (int u = 0; u < 4; ++u) {
                yl = fmaf(a[r + u], lp[2 * u], yl);
                yl = fmaf(b[r + u], lp[2 * u + 1], yl);
                yh = fmaf(a[r + u], hp[2 * u], yh);
                yh = fmaf(b[r + u], hp[2 * u + 1], yh);
            }
            float wl = gated(yl, tb_l);
            float wh = gated(yh, tb_h);
            if (EDGE) {
                const bool ok = ((unsigned)(outBase + i0 + r) < (unsigned)Nlev);
                wl = ok ? wl : 0.f;
                wh = ok ? wh : 0.f;
            }
            vl[r] = wl; vh[r] = wh;
        }

        if (LAST) {
            stf4(out + ch_lp * LEout + i0, make_float4(vl[0], vl[1], vl[2], vl[3]));
            stf4(out + ch_hp * LEout + i0, make_float4(vh[0], vh[1], vh[2], vh[3]));
        } else {
            const int j0 = i0 >> 1;
            float* ol = out + ch_lp * (2 * LEout);
            float* oh = out + ch_hp * (2 * LEout);
            *reinterpret_cast<float2*>(ol + j0)         = make_float2(vl[0], vl[2]);
            *reinterpret_cast<float2*>(ol + LEout + j0) = make_float2(vl[1], vl[3]);
            *reinterpret_cast<float2*>(oh + j0)         = make_float2(vh[0], vh[2]);
            *reinterpret_cast<float2*>(oh + LEout + j0) = make_float2(vh[1], vh[3]);
        }
    }
}

// Synthesis r=8: out[g,nl] = sum_q y_lp[j0+q]*lp[kb-2q] + y_hp[j0+q]*hp[kb-2q]
// lp-channel of group g is 2g+(g&1); j0=(nl+1)>>1 local, kb=7-(nl&1). One task/thread.
template<int Sin, int Sout, int G, int Nlev, bool EDGE>
__device__ __forceinline__ void synth8(
    const float* __restrict__ in, float* __restrict__ out,
    const float* __restrict__ lp, const float* __restrict__ hp, int outBase)
{
    constexpr int TPG = Sout / 8;
    constexpr int TOT = G * TPG;
    static_assert(TOT <= TPB, "phase must be single-generation");
    const int task = threadIdx.x;
    if (task < TOT) {
        const int g   = task / TPG;
        const int nl0 = (task - g * TPG) * 8;
        const int sw  = g & 1;

        float ya[8], yb[8];
        {
            const float* p0 = in + (2 * g + sw)     * Sin + nl0 / 2;   // lp channel
            const float* p1 = in + (2 * g + 1 - sw) * Sin + nl0 / 2;   // hp channel
            reinterpret_cast<float4*>(ya)[0] = ldf4(p0);
            reinterpret_cast<float4*>(ya)[1] = ldf4(p0 + 4);
            reinterpret_cast<float4*>(yb)[0] = ldf4(p1);
            reinterpret_cast<float4*>(yb)[1] = ldf4(p1 + 4);
        }

        float o[8];
#pragma unroll
        for (int r = 0; r < 8; ++r) {
            const int jr = (r + 1) >> 1;
            const int kb = 7 - (r & 1);
            float acc = 0.f;
#pragma unroll
            for (int q = 0; q < 4; ++q) {
                acc = fmaf(ya[jr + q], lp[kb - 2 * q], acc);
                acc = fmaf(yb[jr + q], hp[kb - 2 * q], acc);
            }
            if (EDGE) {
                const bool ok = ((unsigned)(outBase + nl0 + r) < (unsigned)Nlev);
                acc = ok ? acc : 0.f;
            }
            o[r] = acc;
        }
        float* op = out + g * Sout + nl0;
        stf4(op,     make_float4(o[0], o[1], o[2], o[3]));
        stf4(op + 4, make_float4(o[4], o[5], o[6], o[7]));
    }
}

template<bool EDGE>
__device__ __forceinline__ void run_chunk(
    const float* __restrict__ xb, float* __restrict__ ob, int s,
    float* __restrict__ bufA, float* __restrict__ bufB,
    const float* __restrict__ lp, const float* __restrict__ hp,
    const float* __restrict__ bss)
{
    const int tid = threadIdx.x;

    // Stage x window, base s-221: E[j]=x[base+2j] (bufA[0..763]), O[j]=x[base+2j+1]
    {
        const int base = s - 221;
#pragma unroll
        for (int k = 0; k < 4; ++k) {
            const int j = tid + 192 * k;
            if (j < 764) {
                const int g0 = base + 2 * j;
                if (EDGE) {
                    bufA[j]       = ((unsigned)g0       < (unsigned)NSEQ) ? xb[g0]     : 0.f;
                    bufA[764 + j] = ((unsigned)(g0 + 1) < (unsigned)NSEQ) ? xb[g0 + 1] : 0.f;
                } else {
                    bufA[j]       = xb[g0];
                    bufA[764 + j] = xb[g0 + 1];
                }
            }
        }
    }
    __syncthreads();

    // ---- analysis (r=4, parity ping-pong); task counts 190,188,184,176,160 ----
    analysis4<764, 380, 760,  1, 16384, EDGE, false>(bufA, bufB, lp, hp, bss + 0,  (s >> 1) - 109);
    __syncthreads();
    analysis4<380, 188, 376,  2,  8192, EDGE, false>(bufB, bufA, lp, hp, bss + 2,  (s >> 2) - 53);
    __syncthreads();
    analysis4<188,  92, 184,  4,  4096, EDGE, false>(bufA, bufB, lp, hp, bss + 6,  (s >> 3) - 25);
    __syncthreads();
    analysis4< 92,  44,  88,  8,  2048, EDGE, false>(bufB, bufA, lp, hp, bss + 14, (s >> 4) - 11);
    __syncthreads();
    analysis4< 44,  40,  40, 16,  1024, EDGE, true >(bufA, bufB, lp, hp, bss + 30, (s >> 5) - 4);
    __syncthreads();

    // ---- synthesis; task counts 144,136,132,130 ----
    synth8< 40,  72, 16,  2048, EDGE>(bufB, bufA, lp, hp, (s >> 4) - 4);
    __syncthreads();
    synth8< 72, 136,  8,  4096, EDGE>(bufA, bufB, lp, hp, (s >> 3) - 4);
    __syncthreads();
    synth8<136, 264,  4,  8192, EDGE>(bufB, bufA, lp, hp, (s >> 2) - 4);
    __syncthreads();
    synth8<264, 520,  2, 16384, EDGE>(bufA, bufB, lp, hp, (s >> 1) - 4);
    __syncthreads();

    // ---- final level (G=1) straight to global; recon1 in bufB, stride 520, base s/2-4 ----
    if (tid < 128) {
        const int i0 = tid * 8;
        float ya[12], yb[12];
        {
            const float* p0 = bufB + i0 / 2;          // channel 0 = lp
            const float* p1 = p0 + 520;               // channel 1 = hp
            reinterpret_cast<float4*>(ya)[0] = ldf4(p0);
            reinterpret_cast<float4*>(ya)[1] = ldf4(p0 + 4);
            reinterpret_cast<float4*>(ya)[2] = ldf4(p0 + 8);
            reinterpret_cast<float4*>(yb)[0] = ldf4(p1);
            reinterpret_cast<float4*>(yb)[1] = ldf4(p1 + 4);
            reinterpret_cast<float4*>(yb)[2] = ldf4(p1 + 8);
        }
        float o[8];
#pragma unroll
        for (int r = 0; r < 8; ++r) {
            const int jr = ((r + 1) >> 1) + 2;
            const int kb = 7 - (r & 1);
            float acc = 0.f;
#pragma unroll
            for (int q = 0; q < 4; ++q) {
                acc = fmaf(ya[jr + q], lp[kb - 2 * q], acc);
                acc = fmaf(yb[jr + q], hp[kb - 2 * q], acc);
            }
            o[r] = acc;
        }
        stf4(ob + i0,     make_float4(o[0], o[1], o[2], o[3]));
        stf4(ob + i0 + 4, make_float4(o[4], o[5], o[6], o[7]));
    }
}

__global__ __launch_bounds__(TPB, 7) void wpt_fused(
    const float* __restrict__ x,
    const float* __restrict__ K1, const float* __restrict__ K2,
    const float* __restrict__ K3, const float* __restrict__ K4,
    const float* __restrict__ K5,
    const float* __restrict__ B1, const float* __restrict__ B2,
    const float* __restrict__ B3, const float* __restrict__ B4,
    const float* __restrict__ B5,
    float* __restrict__ out)
{
    __shared__ __align__(16) float bufA[1528];
    __shared__ __align__(16) float bufB[1520];
    __shared__ float bss[62];

    const int tid   = threadIdx.x;
    const int batch = blockIdx.x >> 5;
    const int cid   = blockIdx.x & 31;
    const int s     = cid * C0;

    // Filters in SGPRs: K1 = [lp | hp]; every level's rows are one of these two.
    float lp[8], hp[8];
#pragma unroll
    for (int t = 0; t < 8; ++t) {
        lp[t] = rfl(K1[t]);
        hp[t] = rfl(K1[8 + t]);
    }

    // Biases (pre-scaled by 10*log2(e)); 62 total, one pass with TPB=192
    {
        const float* bin[5] = {B1, B2, B3, B4, B5};
        const int boff[5] = {0, 2, 6, 14, 30};
#pragma unroll
        for (int l = 0; l < 5; ++l)
            for (int i = tid; i < (2 << l); i += TPB) bss[boff[l] + i] = SCG * bin[l][i];
    }

    const float* xb = x + batch * NSEQ;
    float* ob = out + batch * NSEQ + s;

    if (cid == 0 || cid == 31)
        run_chunk<true >(xb, ob, s, bufA, bufB, lp, hp, bss);
    else
        run_chunk<false>(xb, ob, s, bufA, bufB, lp, hp, bss);
}

extern "C" void kernel_launch(void* const* d_in, const int* in_sizes, int n_in,
                              void* d_out, int out_size, void* d_ws, size_t ws_size,
                              hipStream_t stream) {
    const int nbatch = in_sizes[0] / NSEQ;
    wpt_fused<<<dim3(nbatch * (NSEQ / C0)), dim3(TPB), 0, stream>>>(
        (const float*)d_in[0],
        (const float*)d_in[1], (const float*)d_in[2],
        (const float*)d_in[3], (const float*)d_in[4],
        (const float*)d_in[5],
        (const float*)d_in[6], (const float*)d_in[7],
        (const float*)d_in[8], (const float*)d_in[9],
        (const float*)d_in[10],
        (float*)d_out);
}